// Round 10
// baseline (259.482 us; speedup 1.0000x reference)
//
#include <hip/hip_runtime.h>
#include <math.h>

#define NEL 10
#define FD 64
#define NBES 8
#define GG 20
#define HML 16
#define EGB 1280  // geom blocks (polpart rows): 1 edge/thread
#define NUB 5000  // node_update blocks = N/4

typedef __attribute__((ext_vector_type(8))) short short8;
typedef __attribute__((ext_vector_type(4))) float f32x4;

__device__ __forceinline__ float wred(float v) {
    #pragma unroll
    for (int off = 32; off > 0; off >>= 1) v += __shfl_down(v, off, 64);
    return v;
}

__device__ __forceinline__ float silu(float h) {
    return h / (1.f + __expf(-h));
}

__device__ __forceinline__ unsigned short f2bf(float x) {
    unsigned int b = __float_as_uint(x);
    unsigned int r = (b + 0x7FFFu + ((b >> 16) & 1u)) >> 16;
    return (unsigned short)r;
}

// RNE-pack two f32 -> packed bf16 pair (low=a, high=b). Bit-identical to f2bf.
__device__ __forceinline__ unsigned int cvt_pk_bf16(float a, float b) {
    unsigned int r;
    asm("v_cvt_pk_bf16_f32 %0, %1, %2" : "=v"(r) : "v"(a), "v"(b));
    return r;
}

// bijective XCD-aware block swizzle (m204 form); contiguous chunk per XCD
__device__ __forceinline__ int xcd_swizzle(int bid, int nb) {
    int q = nb >> 3, r = nb & 7;
    int x = bid & 7, i = bid >> 3;
    return (x < r ? x * (q + 1) : r * (q + 1) + (x - r) * q) + i;
}

// Receiver histogram only (tiny; runs before scan).
__global__ __launch_bounds__(256) void hist_k(
    const int* __restrict__ eidx, int* __restrict__ cnt, int E_)
{
    int e = blockIdx.x * 256 + threadIdx.x;
    atomicAdd(&cnt[eidx[E_ + e]], 1);
}

// Single-block shuffle scan (pure prefix-sum of receiver counts).
__global__ __launch_bounds__(1024) void scan_k(
    const int* __restrict__ cnt, int* __restrict__ cur, int N_)
{
    int t = threadIdx.x;
    __shared__ int wtot[16];
    int lane = t & 63, wid = t >> 6;
    int base = t * 20;
    int c[20]; int s = 0;
    bool full = (base + 20 <= N_);
    if (full) {
        #pragma unroll
        for (int i = 0; i < 5; ++i) {
            int4 v4 = *(const int4*)&cnt[base + i * 4];
            c[i*4+0] = v4.x; c[i*4+1] = v4.y; c[i*4+2] = v4.z; c[i*4+3] = v4.w;
        }
        #pragma unroll
        for (int i = 0; i < 20; ++i) s += c[i];
    } else {
        #pragma unroll
        for (int i = 0; i < 20; ++i) { int idx = base + i; c[i] = (idx < N_) ? cnt[idx] : 0; s += c[i]; }
    }
    int v = s;
    #pragma unroll
    for (int off = 1; off < 64; off <<= 1) {
        int u = __shfl_up(v, off, 64);
        if (lane >= off) v += u;
    }
    if (lane == 63) wtot[wid] = v;
    __syncthreads();
    if (wid == 0 && lane < 16) {
        int wv = wtot[lane];
        #pragma unroll
        for (int off = 1; off < 16; off <<= 1) {
            int u = __shfl_up(wv, off, 64);
            if (lane >= off) wv += u;
        }
        wtot[lane] = wv;
    }
    __syncthreads();
    int ex = (wid > 0 ? wtot[wid - 1] : 0) + (v - s);
    if (full) {
        int o[20];
        #pragma unroll
        for (int i = 0; i < 20; ++i) { o[i] = ex; ex += c[i]; }
        #pragma unroll
        for (int i = 0; i < 5; ++i)
            *(int4*)&cur[base + i * 4] = make_int4(o[i*4+0], o[i*4+1], o[i*4+2], o[i*4+3]);
    } else {
        #pragma unroll
        for (int i = 0; i < 20; ++i) {
            int idx = base + i;
            if (idx < N_) { cur[idx] = ex; ex += c[i]; }
        }
    }
}

// Fused: blocks [0,EGB) = geom scatter; [EGB,EGB+36) = weight conv + out zero;
// [EGB+36, EGB+36+N/4) = node init; [EGB+36+N/4, +1250) = agg0 zero (float4).
// All setup work runs concurrently with (hides under) the geom scatter.
__global__ __launch_bounds__(256) void setup_geom_k(
    const float* __restrict__ pos, const int* __restrict__ eidx,
    const float* __restrict__ flux_w, int* __restrict__ cur,
    unsigned short* __restrict__ bessel, unsigned int* __restrict__ ids,
    float* __restrict__ polpart,
    const float* __restrict__ attrs, const float* __restrict__ ae,
    const float* __restrict__ fc, const float* __restrict__ embed_w,
    int* __restrict__ spec, float* __restrict__ q, float* __restrict__ out,
    float* __restrict__ scal, float* __restrict__ agg0,
    const float* __restrict__ w1, const float* __restrict__ w2,
    unsigned short* __restrict__ w1bf, unsigned short* __restrict__ w2bf,
    int N_, int E_, int ng)
{
    int bid = blockIdx.x, t = threadIdx.x;
    if (bid < EGB) {
        // ---- geom scatter path (1 edge/thread) ----
        __shared__ float lpol[GG * 3];
        for (int i = t; i < GG * 3; i += 256) lpol[i] = 0.f;
        __syncthreads();
        int e = bid * 256 + t;
        if (e < E_) {
            float fw[NBES];
            #pragma unroll
            for (int i = 0; i < NBES; ++i) fw[i] = flux_w[i] + flux_w[NBES + i];
            unsigned int magic = (unsigned int)(0xFFFFFFFFull / (unsigned int)ng) + 1u;
            const float PI = 3.14159265358979323846f;
            int s = eidx[e], r = eidx[E_ + e];
            float dx = pos[(size_t)r*3+0] - pos[(size_t)s*3+0];
            float dy = pos[(size_t)r*3+1] - pos[(size_t)s*3+1];
            float dz = pos[(size_t)r*3+2] - pos[(size_t)s*3+2];
            float len = sqrtf(dx*dx + dy*dy + dz*dz + 1e-12f);
            float x = len * 0.2f;
            float u = 0.f;
            if (x < 1.f) {
                float x2 = x * x;
                float x5 = x2 * x2 * x;
                u = 1.f - 21.f * x5 + 35.f * x5 * x - 15.f * x5 * x2;
            }
            float pref = 0.6324555320336759f / len * u;
            float theta = PI * x;
            float s1, c1;
            __sincosf(theta, &s1, &c1);
            float c2 = 2.f * c1;
            float sp_ = 0.f, sn = s1;
            float flux = 0.f;
            unsigned int pk[4];
            #pragma unroll
            for (int i = 0; i < 4; ++i) {
                float r0 = pref * sn;
                float n1 = c2 * sn - sp_; sp_ = sn; sn = n1;
                float r1 = pref * sn;
                n1 = c2 * sn - sp_; sp_ = sn; sn = n1;
                flux += r0 * fw[2*i] + r1 * fw[2*i+1];
                pk[i] = cvt_pk_bf16(r0, r1);
            }
            int p = atomicAdd(&cur[r], 1);
            *(uint4*)&bessel[(size_t)p * NBES] = make_uint4(pk[0], pk[1], pk[2], pk[3]);
            ids[p] = (unsigned int)s | ((unsigned int)r << 16);
            int g = (int)__umulhi((unsigned int)r, magic);
            atomicAdd(&lpol[g*3+0], flux * dx);
            atomicAdd(&lpol[g*3+1], flux * dy);
            atomicAdd(&lpol[g*3+2], flux * dz);
        }
        __syncthreads();
        for (int i = t; i < GG * 3; i += 256) polpart[bid * (GG * 3) + i] = lpol[i];
    } else if (bid < EGB + 36) {
        // ---- weight conversion + out[0..GG) zero ----
        int idx = (bid - EGB) * 256 + t;
        if (idx < 8192) {
            int l = idx >> 12, rem = idx & 4095;
            int f = rem >> 6, k = rem & 63;
            w2bf[idx] = f2bf(w2[l * 4096 + k * 64 + f]);
        } else {
            int j = idx - 8192;
            int l = j >> 9, rem = j & 511;
            int mm = rem >> 3, jj = rem & 7;
            w1bf[j] = f2bf(w1[l * 512 + jj * 64 + mm]);
        }
        if (idx < GG) out[idx] = 0.f;     // total-energy accumulators
    } else if (bid < EGB + 36 + (N_ >> 2)) {
        // ---- node init: scal embed, spec, q=fc, E0 ----
        int idx = (bid - (EGB + 36)) * 256 + t;
        int lane = t & 63;
        int n = idx >> 6;
        bool pred = (lane < NEL) && (attrs[(size_t)n * NEL + lane] > 0.5f);
        unsigned long long m = __ballot(pred);
        int sp = (int)__builtin_ctzll(m);
        scal[idx] = embed_w[sp * FD + lane];
        if (lane == 0) { spec[n] = sp; q[n] = fc[sp]; out[GG + n] = ae[sp]; }
    } else {
        // ---- agg0 zero (float4 stores; replaces 5.1 MB of the memset) ----
        int idx = (bid - (EGB + 36 + (N_ >> 2))) * 256 + t;
        f32x4 z = {0.f, 0.f, 0.f, 0.f};
        *(f32x4*)&agg0[(size_t)idx * 4] = z;
    }
}

// Radial MLP (both phases MFMA) + segmented scatter. 64 edges/wave,
// 1-wave (64-thread) blocks: kernel has no cross-wave sync and wave-private
// LDS, so smaller blocks raise resident waves/CU 8 -> ~19.5 (R5 PMC showed
// occupancy was grid-limited at 4-wave blocks, not resource-limited).
// Interior segmented runs -> plain store; wave-boundary runs atomicAdd.
__global__ __launch_bounds__(64, 8) void edge_mlp_k(
    const unsigned short* __restrict__ bessel, const unsigned int* __restrict__ ids,
    const unsigned short* __restrict__ w1bf, const float* __restrict__ b1,
    const unsigned short* __restrict__ w2bf, const float* __restrict__ scal,
    float* __restrict__ agg0, int layer, int E_)
{
    __shared__ __align__(16) char smem[4352];
    int lane = threadIdx.x;
    int mrow = lane & 15, quad = lane >> 4;
    int xb = xcd_swizzle(blockIdx.x, gridDim.x);
    int wbase = xb * 64;
    unsigned short* hw = (unsigned short*)smem;
    float* cw = (float*)smem;

    unsigned int ids_all = ids[wbase + lane];   // one coalesced u32/lane = 64 edges
    int firstR = (int)(__builtin_amdgcn_readlane(ids_all, 0) >> 16);

    const short8 z8 = {0,0,0,0,0,0,0,0};
    short8 a1f[4];
    #pragma unroll
    for (int nt = 0; nt < 4; ++nt) {
        a1f[nt] = z8;
        if (quad == 0) a1f[nt] = *(const short8*)&w1bf[layer * 512 + (nt * 16 + mrow) * 8];
        else if (quad == 1) a1f[nt][0] = (short)f2bf(b1[layer * FD + nt * 16 + mrow]);
    }
    const unsigned short* wb = w2bf + layer * 4096;
    short8 bf0[4], bf1[4];
    #pragma unroll
    for (int nt = 0; nt < 4; ++nt) {
        bf0[nt] = *(const short8*)&wb[(nt * 16 + mrow) * 64 + quad * 8];
        bf1[nt] = *(const short8*)&wb[(nt * 16 + mrow) * 64 + 32 + quad * 8];
    }

    f32x4 zf = {0.f, 0.f, 0.f, 0.f};
    int curR = firstR;
    float run = 0.f;

    #pragma unroll 1
    for (int grp = 0; grp < 4; ++grp) {
        int ebase = wbase + grp * 16;

        short8 b_ef = z8;
        if (quad == 0) b_ef = *(const short8*)&bessel[(size_t)(ebase + mrow) * NBES];
        else if (quad == 1) b_ef[0] = (short)0x3F80;     // bf16(1.0) bias slot

        // phase 1: h^T = [W1^T|b1] @ [ef|1]^T  (4 MFMAs), silu, cvt_pk -> hw
        #pragma unroll
        for (int nt = 0; nt < 4; ++nt) {
            f32x4 c1 = __builtin_amdgcn_mfma_f32_16x16x32_bf16(a1f[nt], b_ef, zf, 0, 0, 0);
            unsigned int p01 = cvt_pk_bf16(silu(c1[0]), silu(c1[1]));
            unsigned int p23 = cvt_pk_bf16(silu(c1[2]), silu(c1[3]));
            *(uint2*)&hw[mrow * 72 + nt * 16 + quad * 4] = make_uint2(p01, p23);
        }

        // phase 2: A = h @ W2 (8 MFMAs)
        short8 a0  = *(const short8*)&hw[mrow * 72 + quad * 8];
        short8 a1b = *(const short8*)&hw[mrow * 72 + 32 + quad * 8];
        f32x4 c[4];
        #pragma unroll
        for (int nt = 0; nt < 4; ++nt) {
            f32x4 cc = __builtin_amdgcn_mfma_f32_16x16x32_bf16(a0, bf0[nt], zf, 0, 0, 0);
            cc = __builtin_amdgcn_mfma_f32_16x16x32_bf16(a1b, bf1[nt], cc, 0, 0, 0);
            c[nt] = cc;
        }
        #pragma unroll
        for (int nt = 0; nt < 4; ++nt)
            #pragma unroll
            for (int reg = 0; reg < 4; ++reg)
                cw[(quad * 4 + reg) * 68 + nt * 16 + mrow] = c[nt][reg];

        // epilogue: batched loads, segmented reduce carried across sub-tiles
        #pragma unroll
        for (int half = 0; half < 2; ++half) {
            float cv[8], sw[8];
            unsigned int idv[8];
            #pragma unroll
            for (int k = 0; k < 8; ++k) {
                int pp = half * 8 + k;
                cv[k] = cw[pp * 68 + lane];
                idv[k] = __builtin_amdgcn_readlane(ids_all, grp * 16 + pp);
                sw[k] = scal[(size_t)(idv[k] & 0xffffu) * FD + lane];
            }
            #pragma unroll
            for (int k = 0; k < 8; ++k) {
                int r = (int)(idv[k] >> 16);
                float v = cv[k] * sw[k];
                if (r != curR) {
                    float* dst = &agg0[(size_t)curR * FD + lane];
                    if (curR != firstR) *dst = run;       // interior run: exclusive owner
                    else atomicAdd(dst, run);             // wave-boundary run
                    run = v; curR = r;
                } else {
                    run += v;
                }
            }
        }
    }
    atomicAdd(&agg0[(size_t)curR * FD + lane], run);       // trailing boundary run
}

// Node update + block-level energy partial (nEpart[layer][block]).
__global__ __launch_bounds__(256) void node_update_k(
    float* __restrict__ scal, float* __restrict__ agg0,
    const int* __restrict__ spec, const float* __restrict__ prod_w,
    const float* __restrict__ readout_w, const float* __restrict__ ro2_w1,
    const float* __restrict__ ro2_b1, const float* __restrict__ ro2_w2,
    const float* __restrict__ charge_w, float* __restrict__ q,
    float* __restrict__ out_nodeE, float* __restrict__ nEpart,
    int layer, int last, int N_)
{
    __shared__ float vsh[4][FD];
    __shared__ float red[4];
    int wid = threadIdx.x >> 6, lane = threadIdx.x & 63;
    int n = blockIdx.x * 4 + wid;
    int sp = spec[n];
    size_t idx = (size_t)n * FD + lane;
    float a = agg0[idx] * 0.0625f;
    if (!last) agg0[idx] = 0.f;            // last layer: agg0 never read again
    float v = a + a * a + scal[idx] * prod_w[(layer * NEL + sp) * FD + lane];
    scal[idx] = v;

    float ne;
    if (!last) {
        ne = wred(v * readout_w[layer * FD + lane]);
    } else {
        vsh[wid][lane] = v;                    // wave-private, in-order DS
        float h = 0.f;
        if (lane < HML) {
            h = ro2_b1[lane];
            for (int ff = 0; ff < FD; ++ff) h += vsh[wid][ff] * ro2_w1[ff * HML + lane];
            h = silu(h) * ro2_w2[lane];
        }
        ne = wred(h);
    }
    float qs = wred(v * charge_w[layer * FD + lane]);
    if (lane == 0) {
        out_nodeE[n] += ne;
        q[n] += qs;
        red[wid] = ne;
    }
    __syncthreads();
    if (threadIdx.x == 0) nEpart[layer * NUB + blockIdx.x] = red[0] + red[1] + red[2] + red[3];
}

// Coulomb via triangular 64x64 chunk pairs (136/graph) + 1 reduce block/graph.
__global__ __launch_bounds__(256) void coulomb_final_k(
    const float* __restrict__ q, const float* __restrict__ pos,
    const int* __restrict__ spec, const float* __restrict__ ae,
    const float* __restrict__ fc, const float* __restrict__ nEpart,
    const float* __restrict__ polpart, float* __restrict__ out,
    int N_, int ng)
{
    __shared__ float sh[260];
    int vb = blockIdx.x;
    int g = vb / 137, rem = vb % 137;
    int t = threadIdx.x, lane = t & 63, w = t >> 6;

    if (rem < 136) {
        int a = 0, r2 = rem;
        while (r2 >= 16 - a) { r2 -= 16 - a; ++a; }
        int b = a + r2;
        const float* qg = q + (size_t)g * ng;
        const float* pg = pos + (size_t)g * ng * 3;
        float* qs_ = sh; float* jx = sh + 64; float* jy = sh + 128; float* jz = sh + 192;
        if (t < 64) {
            int j = b * 64 + t;
            bool ok = j < ng;
            qs_[t] = ok ? qg[j] : 0.f;
            jx[t] = ok ? pg[(size_t)j*3+0] : 0.f;
            jy[t] = ok ? pg[(size_t)j*3+1] : 0.f;
            jz[t] = ok ? pg[(size_t)j*3+2] : 0.f;
        }
        __syncthreads();
        int i = a * 64 + lane;
        float accu = 0.f;
        if (i < ng) {
            float qi = qg[i];
            float xi = pg[(size_t)i*3+0], yi = pg[(size_t)i*3+1], zi = pg[(size_t)i*3+2];
            #pragma unroll 4
            for (int k = 0; k < 16; ++k) {
                int jj = w * 16 + k;                  // wave-uniform -> LDS broadcast
                int j = b * 64 + jj;
                float dx = xi - jx[jj], dy = yi - jy[jj], dz = zi - jz[jj];
                float d2 = dx*dx + dy*dy + dz*dz + 1e-12f;
                float rinv = __frsqrt_rn(d2);
                float r = d2 * rinv;
                float x = 0.5f * r;
                float tt = __frcp_rn(1.f + 0.3275911f * x);
                float poly = ((((1.061405429f*tt - 1.453152027f)*tt + 1.421413741f)*tt
                               - 0.284496736f)*tt + 0.254829592f)*tt;
                float erfv = 1.f - poly * __expf(-x * x);
                float kern = (j == i) ? 0.f : erfv * rinv;
                accu += qi * qs_[jj] * kern;
            }
        }
        accu = wred(accu);
        if (lane == 0) sh[256 + w] = accu;
        __syncthreads();
        if (t == 0) {
            float s = sh[256] + sh[257] + sh[258] + sh[259];
            atomicAdd(&out[g], (a == b) ? 0.5f * s : s);
        }
    } else {
        float se0 = 0.f, sq = 0.f, p0 = 0.f, p1 = 0.f, p2 = 0.f, s0 = 0.f, s1 = 0.f;
        for (int n = g * ng + t; n < (g + 1) * ng; n += 256) {
            int sp = spec[n];
            float fq = fc[sp];
            se0 += ae[sp];
            sq += q[n];
            p0 += fq * pos[(size_t)n*3+0];
            p1 += fq * pos[(size_t)n*3+1];
            p2 += fq * pos[(size_t)n*3+2];
        }
        if (t < 250) {
            int b = g * 250 + t;
            s0 = nEpart[b];
            s1 = nEpart[NUB + b];
        }
        for (int b = t; b < EGB; b += 256) {
            p0 += polpart[b * (GG * 3) + g * 3 + 0];
            p1 += polpart[b * (GG * 3) + g * 3 + 1];
            p2 += polpart[b * (GG * 3) + g * 3 + 2];
        }
        float vals[7] = {se0, s0, s1, sq, p0, p1, p2};
        float* red = sh;
        #pragma unroll
        for (int k = 0; k < 7; ++k) {
            float r = wred(vals[k]);
            if (lane == 0) red[w * 8 + k] = r;
        }
        __syncthreads();
        if (t < 7) sh[64 + t] = red[t] + red[8 + t] + red[16 + t] + red[24 + t];
        __syncthreads();
        if (t == 0) {
            float a0 = sh[64], a1 = sh[65], a2 = sh[66];
            atomicAdd(&out[g], a0 + a1 + a2);
            float* contrib = out + GG + N_;
            contrib[g*3+0] = a0; contrib[g*3+1] = a1; contrib[g*3+2] = a2;
            float* pol = contrib + GG * 3;
            pol[g*3+0] = sh[68]; pol[g*3+1] = sh[69]; pol[g*3+2] = sh[70];
            float* qt = pol + GG * 3;
            qt[g] = sh[67];
        }
    }
}

extern "C" void kernel_launch(void* const* d_in, const int* in_sizes, int n_in,
                              void* d_out, int out_size, void* d_ws, size_t ws_size,
                              hipStream_t stream)
{
    const float* node_attrs      = (const float*)d_in[0];
    const float* positions       = (const float*)d_in[1];
    const int*   edge_index      = (const int*)d_in[2];
    const float* atomic_energies = (const float*)d_in[5];
    const float* embed_w         = (const float*)d_in[6];
    const float* radial_w1       = (const float*)d_in[7];
    const float* radial_b1       = (const float*)d_in[8];
    const float* radial_w2       = (const float*)d_in[9];
    const float* prod_w          = (const float*)d_in[10];
    const float* readout_w       = (const float*)d_in[11];
    const float* ro2_w1          = (const float*)d_in[12];
    const float* ro2_b1          = (const float*)d_in[13];
    const float* ro2_w2          = (const float*)d_in[14];
    const float* charge_w        = (const float*)d_in[15];
    const float* flux_w          = (const float*)d_in[16];
    const float* formal_charges  = (const float*)d_in[17];

    int N = in_sizes[0] / NEL;     // 20000
    int E = in_sizes[2] / 2;       // 320000
    int ng = N / GG;               // 1000

    float* ws      = (float*)d_ws;
    float* scal    = ws;                                   // [N,64]
    float* agg0    = scal + (size_t)N * FD;                // [N,64]  (zeroed in setup_geom)
    int*   cnt     = (int*)(agg0 + (size_t)N * FD);        // [N]     (memset)
    int*   cur     = cnt + N;                              // [N]
    unsigned short* bessel = (unsigned short*)(cur + N);   // [E,8] bf16 sorted (16B/edge)
    unsigned int*   ids    = (unsigned int*)(bessel + (size_t)E * NBES); // [E] snd|rcv<<16
    float* q       = (float*)(ids + E);                    // [N]
    int*   spec    = (int*)(q + N);                        // [N]
    float* nEpart  = (float*)(spec + N);                   // [2*NUB]
    float* polpart = nEpart + 2 * NUB;                     // [EGB*60]
    unsigned short* w2bf = (unsigned short*)(polpart + EGB * (GG * 3)); // [2*4096]
    unsigned short* w1bf = w2bf + 8192;                    // [2*512]

    float* out = (float*)d_out;
    float* out_nodeE = out + GG;

    hipMemsetAsync(cnt, 0, (size_t)N * sizeof(int), stream);

    hist_k<<<E / 256, 256, 0, stream>>>(edge_index, cnt, E);
    scan_k<<<1, 1024, 0, stream>>>(cnt, cur, N);
    setup_geom_k<<<EGB + 36 + N / 4 + (N * FD) / 1024, 256, 0, stream>>>(
        positions, edge_index, flux_w, cur, bessel, ids, polpart,
        node_attrs, atomic_energies, formal_charges, embed_w,
        spec, q, out, scal, agg0, radial_w1, radial_w2, w1bf, w2bf, N, E, ng);

    for (int l = 0; l < 2; ++l) {
        edge_mlp_k<<<E / 64, 64, 0, stream>>>(
            bessel, ids, w1bf, radial_b1, w2bf, scal, agg0, l, E);
        node_update_k<<<N / 4, 256, 0, stream>>>(
            scal, agg0, spec, prod_w, readout_w, ro2_w1, ro2_b1, ro2_w2,
            charge_w, q, out_nodeE, nEpart, l, (l == 1) ? 1 : 0, N);
    }

    coulomb_final_k<<<GG * 137, 256, 0, stream>>>(
        q, positions, spec, atomic_energies, formal_charges,
        nEpart, polpart, out, N, ng);
}

// Round 11
// 243.622 us; speedup vs baseline: 1.0651x; 1.0651x over previous
//
#include <hip/hip_runtime.h>
#include <math.h>

#define NEL 10
#define FD 64
#define NBES 8
#define GG 20
#define HML 16
#define EGB 1280  // geom blocks (polpart rows): 1 edge/thread
#define NUB 5000  // node_update blocks = N/4

typedef __attribute__((ext_vector_type(8))) short short8;
typedef __attribute__((ext_vector_type(4))) float f32x4;

__device__ __forceinline__ float wred(float v) {
    #pragma unroll
    for (int off = 32; off > 0; off >>= 1) v += __shfl_down(v, off, 64);
    return v;
}

__device__ __forceinline__ float silu(float h) {
    return h / (1.f + __expf(-h));
}

__device__ __forceinline__ unsigned short f2bf(float x) {
    unsigned int b = __float_as_uint(x);
    unsigned int r = (b + 0x7FFFu + ((b >> 16) & 1u)) >> 16;
    return (unsigned short)r;
}

// RNE-pack two f32 -> packed bf16 pair (low=a, high=b). Bit-identical to f2bf.
__device__ __forceinline__ unsigned int cvt_pk_bf16(float a, float b) {
    unsigned int r;
    asm("v_cvt_pk_bf16_f32 %0, %1, %2" : "=v"(r) : "v"(a), "v"(b));
    return r;
}

// bijective XCD-aware block swizzle (m204 form); contiguous chunk per XCD
__device__ __forceinline__ int xcd_swizzle(int bid, int nb) {
    int q = nb >> 3, r = nb & 7;
    int x = bid & 7, i = bid >> 3;
    return (x < r ? x * (q + 1) : r * (q + 1) + (x - r) * q) + i;
}

// Receiver histogram only (tiny; runs before scan).
__global__ __launch_bounds__(256) void hist_k(
    const int* __restrict__ eidx, int* __restrict__ cnt, int E_)
{
    int e = blockIdx.x * 256 + threadIdx.x;
    atomicAdd(&cnt[eidx[E_ + e]], 1);
}

// Single-block shuffle scan (pure prefix-sum of receiver counts).
__global__ __launch_bounds__(1024) void scan_k(
    const int* __restrict__ cnt, int* __restrict__ cur, int N_)
{
    int t = threadIdx.x;
    __shared__ int wtot[16];
    int lane = t & 63, wid = t >> 6;
    int base = t * 20;
    int c[20]; int s = 0;
    bool full = (base + 20 <= N_);
    if (full) {
        #pragma unroll
        for (int i = 0; i < 5; ++i) {
            int4 v4 = *(const int4*)&cnt[base + i * 4];
            c[i*4+0] = v4.x; c[i*4+1] = v4.y; c[i*4+2] = v4.z; c[i*4+3] = v4.w;
        }
        #pragma unroll
        for (int i = 0; i < 20; ++i) s += c[i];
    } else {
        #pragma unroll
        for (int i = 0; i < 20; ++i) { int idx = base + i; c[i] = (idx < N_) ? cnt[idx] : 0; s += c[i]; }
    }
    int v = s;
    #pragma unroll
    for (int off = 1; off < 64; off <<= 1) {
        int u = __shfl_up(v, off, 64);
        if (lane >= off) v += u;
    }
    if (lane == 63) wtot[wid] = v;
    __syncthreads();
    if (wid == 0 && lane < 16) {
        int wv = wtot[lane];
        #pragma unroll
        for (int off = 1; off < 16; off <<= 1) {
            int u = __shfl_up(wv, off, 64);
            if (lane >= off) wv += u;
        }
        wtot[lane] = wv;
    }
    __syncthreads();
    int ex = (wid > 0 ? wtot[wid - 1] : 0) + (v - s);
    if (full) {
        int o[20];
        #pragma unroll
        for (int i = 0; i < 20; ++i) { o[i] = ex; ex += c[i]; }
        #pragma unroll
        for (int i = 0; i < 5; ++i)
            *(int4*)&cur[base + i * 4] = make_int4(o[i*4+0], o[i*4+1], o[i*4+2], o[i*4+3]);
    } else {
        #pragma unroll
        for (int i = 0; i < 20; ++i) {
            int idx = base + i;
            if (idx < N_) { cur[idx] = ex; ex += c[i]; }
        }
    }
}

// Fused: blocks [0,EGB) = geom scatter; [EGB,EGB+36) = weight conv + out zero;
// [EGB+36, ...) = node init (scal/spec/q/E0). The setup work runs
// concurrently with (hides under) the geom scatter.
__global__ __launch_bounds__(256) void setup_geom_k(
    const float* __restrict__ pos, const int* __restrict__ eidx,
    const float* __restrict__ flux_w, int* __restrict__ cur,
    unsigned short* __restrict__ bessel, unsigned int* __restrict__ ids,
    float* __restrict__ polpart,
    const float* __restrict__ attrs, const float* __restrict__ ae,
    const float* __restrict__ fc, const float* __restrict__ embed_w,
    int* __restrict__ spec, float* __restrict__ q, float* __restrict__ out,
    float* __restrict__ scal,
    const float* __restrict__ w1, const float* __restrict__ w2,
    unsigned short* __restrict__ w1bf, unsigned short* __restrict__ w2bf,
    int N_, int E_, int ng)
{
    int bid = blockIdx.x, t = threadIdx.x;
    if (bid < EGB) {
        // ---- geom scatter path (1 edge/thread) ----
        __shared__ float lpol[GG * 3];
        for (int i = t; i < GG * 3; i += 256) lpol[i] = 0.f;
        __syncthreads();
        int e = bid * 256 + t;
        if (e < E_) {
            float fw[NBES];
            #pragma unroll
            for (int i = 0; i < NBES; ++i) fw[i] = flux_w[i] + flux_w[NBES + i];
            unsigned int magic = (unsigned int)(0xFFFFFFFFull / (unsigned int)ng) + 1u;
            const float PI = 3.14159265358979323846f;
            int s = eidx[e], r = eidx[E_ + e];
            float dx = pos[(size_t)r*3+0] - pos[(size_t)s*3+0];
            float dy = pos[(size_t)r*3+1] - pos[(size_t)s*3+1];
            float dz = pos[(size_t)r*3+2] - pos[(size_t)s*3+2];
            float len = sqrtf(dx*dx + dy*dy + dz*dz + 1e-12f);
            float x = len * 0.2f;
            float u = 0.f;
            if (x < 1.f) {
                float x2 = x * x;
                float x5 = x2 * x2 * x;
                u = 1.f - 21.f * x5 + 35.f * x5 * x - 15.f * x5 * x2;
            }
            float pref = 0.6324555320336759f / len * u;
            float theta = PI * x;
            float s1, c1;
            __sincosf(theta, &s1, &c1);
            float c2 = 2.f * c1;
            float sp_ = 0.f, sn = s1;
            float flux = 0.f;
            unsigned int pk[4];
            #pragma unroll
            for (int i = 0; i < 4; ++i) {
                float r0 = pref * sn;
                float n1 = c2 * sn - sp_; sp_ = sn; sn = n1;
                float r1 = pref * sn;
                n1 = c2 * sn - sp_; sp_ = sn; sn = n1;
                flux += r0 * fw[2*i] + r1 * fw[2*i+1];
                pk[i] = cvt_pk_bf16(r0, r1);
            }
            int p = atomicAdd(&cur[r], 1);
            *(uint4*)&bessel[(size_t)p * NBES] = make_uint4(pk[0], pk[1], pk[2], pk[3]);
            ids[p] = (unsigned int)s | ((unsigned int)r << 16);
            int g = (int)__umulhi((unsigned int)r, magic);
            atomicAdd(&lpol[g*3+0], flux * dx);
            atomicAdd(&lpol[g*3+1], flux * dy);
            atomicAdd(&lpol[g*3+2], flux * dz);
        }
        __syncthreads();
        for (int i = t; i < GG * 3; i += 256) polpart[bid * (GG * 3) + i] = lpol[i];
    } else if (bid < EGB + 36) {
        // ---- weight conversion + out[0..GG) zero ----
        int idx = (bid - EGB) * 256 + t;
        if (idx < 8192) {
            int l = idx >> 12, rem = idx & 4095;
            int f = rem >> 6, k = rem & 63;
            w2bf[idx] = f2bf(w2[l * 4096 + k * 64 + f]);
        } else {
            int j = idx - 8192;
            int l = j >> 9, rem = j & 511;
            int mm = rem >> 3, jj = rem & 7;
            w1bf[j] = f2bf(w1[l * 512 + jj * 64 + mm]);
        }
        if (idx < GG) out[idx] = 0.f;     // total-energy accumulators
    } else {
        // ---- node init: scal embed, spec, q=fc, E0 ----
        int idx = (bid - (EGB + 36)) * 256 + t;
        int lane = t & 63;
        int n = idx >> 6;
        bool pred = (lane < NEL) && (attrs[(size_t)n * NEL + lane] > 0.5f);
        unsigned long long m = __ballot(pred);
        int sp = (int)__builtin_ctzll(m);
        scal[idx] = embed_w[sp * FD + lane];
        if (lane == 0) { spec[n] = sp; q[n] = fc[sp]; out[GG + n] = ae[sp]; }
    }
}

// Radial MLP (both phases MFMA) + segmented scatter. 64 edges/wave.
// R4/R9 schedule (compiler-scheduled; all source-level reorderings and
// block repackagings measured worse: R5/R6/R7/R10). Phase-1 pack via
// v_cvt_pk_bf16_f32. Interior segmented runs -> plain store; boundary atomics.
__global__ __launch_bounds__(256, 4) void edge_mlp_k(
    const unsigned short* __restrict__ bessel, const unsigned int* __restrict__ ids,
    const unsigned short* __restrict__ w1bf, const float* __restrict__ b1,
    const unsigned short* __restrict__ w2bf, const float* __restrict__ scal,
    float* __restrict__ agg0, int layer, int E_)
{
    __shared__ __align__(16) char smem[4][4352];
    int t = threadIdx.x, w = t >> 6, lane = t & 63;
    int mrow = lane & 15, quad = lane >> 4;
    int xb = xcd_swizzle(blockIdx.x, gridDim.x);
    int wbase = (xb * 4 + w) * 64;
    unsigned short* hw = (unsigned short*)smem[w];
    float* cw = (float*)smem[w];

    unsigned int ids_all = ids[wbase + lane];   // one coalesced u32/lane = 64 edges
    int firstR = (int)(__builtin_amdgcn_readlane(ids_all, 0) >> 16);

    const short8 z8 = {0,0,0,0,0,0,0,0};
    short8 a1f[4];
    #pragma unroll
    for (int nt = 0; nt < 4; ++nt) {
        a1f[nt] = z8;
        if (quad == 0) a1f[nt] = *(const short8*)&w1bf[layer * 512 + (nt * 16 + mrow) * 8];
        else if (quad == 1) a1f[nt][0] = (short)f2bf(b1[layer * FD + nt * 16 + mrow]);
    }
    const unsigned short* wb = w2bf + layer * 4096;
    short8 bf0[4], bf1[4];
    #pragma unroll
    for (int nt = 0; nt < 4; ++nt) {
        bf0[nt] = *(const short8*)&wb[(nt * 16 + mrow) * 64 + quad * 8];
        bf1[nt] = *(const short8*)&wb[(nt * 16 + mrow) * 64 + 32 + quad * 8];
    }

    f32x4 zf = {0.f, 0.f, 0.f, 0.f};
    int curR = firstR;
    float run = 0.f;

    #pragma unroll 1
    for (int grp = 0; grp < 4; ++grp) {
        int ebase = wbase + grp * 16;

        short8 b_ef = z8;
        if (quad == 0) b_ef = *(const short8*)&bessel[(size_t)(ebase + mrow) * NBES];
        else if (quad == 1) b_ef[0] = (short)0x3F80;     // bf16(1.0) bias slot

        // phase 1: h^T = [W1^T|b1] @ [ef|1]^T  (4 MFMAs), silu, cvt_pk -> hw
        #pragma unroll
        for (int nt = 0; nt < 4; ++nt) {
            f32x4 c1 = __builtin_amdgcn_mfma_f32_16x16x32_bf16(a1f[nt], b_ef, zf, 0, 0, 0);
            unsigned int p01 = cvt_pk_bf16(silu(c1[0]), silu(c1[1]));
            unsigned int p23 = cvt_pk_bf16(silu(c1[2]), silu(c1[3]));
            *(uint2*)&hw[mrow * 72 + nt * 16 + quad * 4] = make_uint2(p01, p23);
        }

        // phase 2: A = h @ W2 (8 MFMAs)
        short8 a0  = *(const short8*)&hw[mrow * 72 + quad * 8];
        short8 a1b = *(const short8*)&hw[mrow * 72 + 32 + quad * 8];
        f32x4 c[4];
        #pragma unroll
        for (int nt = 0; nt < 4; ++nt) {
            f32x4 cc = __builtin_amdgcn_mfma_f32_16x16x32_bf16(a0, bf0[nt], zf, 0, 0, 0);
            cc = __builtin_amdgcn_mfma_f32_16x16x32_bf16(a1b, bf1[nt], cc, 0, 0, 0);
            c[nt] = cc;
        }
        #pragma unroll
        for (int nt = 0; nt < 4; ++nt)
            #pragma unroll
            for (int reg = 0; reg < 4; ++reg)
                cw[(quad * 4 + reg) * 68 + nt * 16 + mrow] = c[nt][reg];

        // epilogue: batched loads, segmented reduce carried across sub-tiles
        #pragma unroll
        for (int half = 0; half < 2; ++half) {
            float cv[8], sw[8];
            unsigned int idv[8];
            #pragma unroll
            for (int k = 0; k < 8; ++k) {
                int pp = half * 8 + k;
                cv[k] = cw[pp * 68 + lane];
                idv[k] = __builtin_amdgcn_readlane(ids_all, grp * 16 + pp);
                sw[k] = scal[(size_t)(idv[k] & 0xffffu) * FD + lane];
            }
            #pragma unroll
            for (int k = 0; k < 8; ++k) {
                int r = (int)(idv[k] >> 16);
                float v = cv[k] * sw[k];
                if (r != curR) {
                    float* dst = &agg0[(size_t)curR * FD + lane];
                    if (curR != firstR) *dst = run;       // interior run: exclusive owner
                    else atomicAdd(dst, run);             // wave-boundary run
                    run = v; curR = r;
                } else {
                    run += v;
                }
            }
        }
    }
    atomicAdd(&agg0[(size_t)curR * FD + lane], run);       // trailing boundary run
}

// Node update + block-level energy partial (nEpart[layer][block]).
// Last-layer MLP wave-parallelized: lane (qq,l) computes a 16-term quarter
// partial of h[l]; two shfl_down(32,16) fold quarters (was: 64-iter serial
// loop on 16/64 lanes).
__global__ __launch_bounds__(256) void node_update_k(
    float* __restrict__ scal, float* __restrict__ agg0,
    const int* __restrict__ spec, const float* __restrict__ prod_w,
    const float* __restrict__ readout_w, const float* __restrict__ ro2_w1,
    const float* __restrict__ ro2_b1, const float* __restrict__ ro2_w2,
    const float* __restrict__ charge_w, float* __restrict__ q,
    float* __restrict__ out_nodeE, float* __restrict__ nEpart,
    int layer, int last, int N_)
{
    __shared__ float vsh[4][FD];
    __shared__ float red[4];
    int wid = threadIdx.x >> 6, lane = threadIdx.x & 63;
    int n = blockIdx.x * 4 + wid;
    int sp = spec[n];
    size_t idx = (size_t)n * FD + lane;
    float a = agg0[idx] * 0.0625f;
    if (!last) agg0[idx] = 0.f;            // last layer: agg0 never read again
    float v = a + a * a + scal[idx] * prod_w[(layer * NEL + sp) * FD + lane];
    scal[idx] = v;

    float ne;
    if (!last) {
        ne = wred(v * readout_w[layer * FD + lane]);
    } else {
        vsh[wid][lane] = v;                    // wave-private, in-order DS
        int l16 = lane & 15, qq = lane >> 4;
        float hp = 0.f;
        #pragma unroll
        for (int ff = 0; ff < 16; ++ff) {
            int fidx = qq * 16 + ff;
            hp += vsh[wid][fidx] * ro2_w1[fidx * HML + l16];
        }
        hp += __shfl_down(hp, 32, 64);
        hp += __shfl_down(hp, 16, 64);         // lanes 0..15 hold full sum
        float h = 0.f;
        if (lane < HML) h = silu(ro2_b1[lane] + hp) * ro2_w2[lane];
        ne = wred(h);
    }
    float qs = wred(v * charge_w[layer * FD + lane]);
    if (lane == 0) {
        out_nodeE[n] += ne;
        q[n] += qs;
        red[wid] = ne;
    }
    __syncthreads();
    if (threadIdx.x == 0) nEpart[layer * NUB + blockIdx.x] = red[0] + red[1] + red[2] + red[3];
}

// Coulomb via triangular 64x64 chunk pairs (136/graph) + 1 reduce block/graph.
__global__ __launch_bounds__(256) void coulomb_final_k(
    const float* __restrict__ q, const float* __restrict__ pos,
    const int* __restrict__ spec, const float* __restrict__ ae,
    const float* __restrict__ fc, const float* __restrict__ nEpart,
    const float* __restrict__ polpart, float* __restrict__ out,
    int N_, int ng)
{
    __shared__ float sh[260];
    int vb = blockIdx.x;
    int g = vb / 137, rem = vb % 137;
    int t = threadIdx.x, lane = t & 63, w = t >> 6;

    if (rem < 136) {
        int a = 0, r2 = rem;
        while (r2 >= 16 - a) { r2 -= 16 - a; ++a; }
        int b = a + r2;
        const float* qg = q + (size_t)g * ng;
        const float* pg = pos + (size_t)g * ng * 3;
        float* qs_ = sh; float* jx = sh + 64; float* jy = sh + 128; float* jz = sh + 192;
        if (t < 64) {
            int j = b * 64 + t;
            bool ok = j < ng;
            qs_[t] = ok ? qg[j] : 0.f;
            jx[t] = ok ? pg[(size_t)j*3+0] : 0.f;
            jy[t] = ok ? pg[(size_t)j*3+1] : 0.f;
            jz[t] = ok ? pg[(size_t)j*3+2] : 0.f;
        }
        __syncthreads();
        int i = a * 64 + lane;
        float accu = 0.f;
        if (i < ng) {
            float qi = qg[i];
            float xi = pg[(size_t)i*3+0], yi = pg[(size_t)i*3+1], zi = pg[(size_t)i*3+2];
            #pragma unroll 4
            for (int k = 0; k < 16; ++k) {
                int jj = w * 16 + k;                  // wave-uniform -> LDS broadcast
                int j = b * 64 + jj;
                float dx = xi - jx[jj], dy = yi - jy[jj], dz = zi - jz[jj];
                float d2 = dx*dx + dy*dy + dz*dz + 1e-12f;
                float rinv = __frsqrt_rn(d2);
                float r = d2 * rinv;
                float x = 0.5f * r;
                float tt = __frcp_rn(1.f + 0.3275911f * x);
                float poly = ((((1.061405429f*tt - 1.453152027f)*tt + 1.421413741f)*tt
                               - 0.284496736f)*tt + 0.254829592f)*tt;
                float erfv = 1.f - poly * __expf(-x * x);
                float kern = (j == i) ? 0.f : erfv * rinv;
                accu += qi * qs_[jj] * kern;
            }
        }
        accu = wred(accu);
        if (lane == 0) sh[256 + w] = accu;
        __syncthreads();
        if (t == 0) {
            float s = sh[256] + sh[257] + sh[258] + sh[259];
            atomicAdd(&out[g], (a == b) ? 0.5f * s : s);
        }
    } else {
        float se0 = 0.f, sq = 0.f, p0 = 0.f, p1 = 0.f, p2 = 0.f, s0 = 0.f, s1 = 0.f;
        for (int n = g * ng + t; n < (g + 1) * ng; n += 256) {
            int sp = spec[n];
            float fq = fc[sp];
            se0 += ae[sp];
            sq += q[n];
            p0 += fq * pos[(size_t)n*3+0];
            p1 += fq * pos[(size_t)n*3+1];
            p2 += fq * pos[(size_t)n*3+2];
        }
        if (t < 250) {
            int b = g * 250 + t;
            s0 = nEpart[b];
            s1 = nEpart[NUB + b];
        }
        for (int b = t; b < EGB; b += 256) {
            p0 += polpart[b * (GG * 3) + g * 3 + 0];
            p1 += polpart[b * (GG * 3) + g * 3 + 1];
            p2 += polpart[b * (GG * 3) + g * 3 + 2];
        }
        float vals[7] = {se0, s0, s1, sq, p0, p1, p2};
        float* red = sh;
        #pragma unroll
        for (int k = 0; k < 7; ++k) {
            float r = wred(vals[k]);
            if (lane == 0) red[w * 8 + k] = r;
        }
        __syncthreads();
        if (t < 7) sh[64 + t] = red[t] + red[8 + t] + red[16 + t] + red[24 + t];
        __syncthreads();
        if (t == 0) {
            float a0 = sh[64], a1 = sh[65], a2 = sh[66];
            atomicAdd(&out[g], a0 + a1 + a2);
            float* contrib = out + GG + N_;
            contrib[g*3+0] = a0; contrib[g*3+1] = a1; contrib[g*3+2] = a2;
            float* pol = contrib + GG * 3;
            pol[g*3+0] = sh[68]; pol[g*3+1] = sh[69]; pol[g*3+2] = sh[70];
            float* qt = pol + GG * 3;
            qt[g] = sh[67];
        }
    }
}

extern "C" void kernel_launch(void* const* d_in, const int* in_sizes, int n_in,
                              void* d_out, int out_size, void* d_ws, size_t ws_size,
                              hipStream_t stream)
{
    const float* node_attrs      = (const float*)d_in[0];
    const float* positions       = (const float*)d_in[1];
    const int*   edge_index      = (const int*)d_in[2];
    const float* atomic_energies = (const float*)d_in[5];
    const float* embed_w         = (const float*)d_in[6];
    const float* radial_w1       = (const float*)d_in[7];
    const float* radial_b1       = (const float*)d_in[8];
    const float* radial_w2       = (const float*)d_in[9];
    const float* prod_w          = (const float*)d_in[10];
    const float* readout_w       = (const float*)d_in[11];
    const float* ro2_w1          = (const float*)d_in[12];
    const float* ro2_b1          = (const float*)d_in[13];
    const float* ro2_w2          = (const float*)d_in[14];
    const float* charge_w        = (const float*)d_in[15];
    const float* flux_w          = (const float*)d_in[16];
    const float* formal_charges  = (const float*)d_in[17];

    int N = in_sizes[0] / NEL;     // 20000
    int E = in_sizes[2] / 2;       // 320000
    int ng = N / GG;               // 1000

    float* ws      = (float*)d_ws;
    float* scal    = ws;                                   // [N,64]
    float* agg0    = scal + (size_t)N * FD;                // [N,64]  (memset)
    int*   cnt     = (int*)(agg0 + (size_t)N * FD);        // [N]     (memset, adjacent)
    int*   cur     = cnt + N;                              // [N]
    unsigned short* bessel = (unsigned short*)(cur + N);   // [E,8] bf16 sorted (16B/edge)
    unsigned int*   ids    = (unsigned int*)(bessel + (size_t)E * NBES); // [E] snd|rcv<<16
    float* q       = (float*)(ids + E);                    // [N]
    int*   spec    = (int*)(q + N);                        // [N]
    float* nEpart  = (float*)(spec + N);                   // [2*NUB]
    float* polpart = nEpart + 2 * NUB;                     // [EGB*60]
    unsigned short* w2bf = (unsigned short*)(polpart + EGB * (GG * 3)); // [2*4096]
    unsigned short* w1bf = w2bf + 8192;                    // [2*512]

    float* out = (float*)d_out;
    float* out_nodeE = out + GG;

    // one memset covers agg0 (zero-init for scatter) + cnt (histogram)
    hipMemsetAsync(agg0, 0, ((size_t)N * FD + N) * sizeof(float), stream);

    hist_k<<<E / 256, 256, 0, stream>>>(edge_index, cnt, E);
    scan_k<<<1, 1024, 0, stream>>>(cnt, cur, N);
    setup_geom_k<<<EGB + 36 + (N * FD) / 256, 256, 0, stream>>>(
        positions, edge_index, flux_w, cur, bessel, ids, polpart,
        node_attrs, atomic_energies, formal_charges, embed_w,
        spec, q, out, scal, radial_w1, radial_w2, w1bf, w2bf, N, E, ng);

    for (int l = 0; l < 2; ++l) {
        edge_mlp_k<<<E / 256, 256, 0, stream>>>(
            bessel, ids, w1bf, radial_b1, w2bf, scal, agg0, l, E);
        node_update_k<<<N / 4, 256, 0, stream>>>(
            scal, agg0, spec, prod_w, readout_w, ro2_w1, ro2_b1, ro2_w2,
            charge_w, q, out_nodeE, nEpart, l, (l == 1) ? 1 : 0, N);
    }

    coulomb_final_k<<<GG * 137, 256, 0, stream>>>(
        q, positions, spec, atomic_energies, formal_charges,
        nEpart, polpart, out, N, ng);
}

// Round 12
// 229.218 us; speedup vs baseline: 1.1320x; 1.0628x over previous
//
#include <hip/hip_runtime.h>
#include <math.h>

#define NEL 10
#define FD 64
#define NBES 8
#define GG 20
#define HML 16
#define EGB 1280  // geom blocks (polpart rows): 1 edge/thread
#define NUB 5000  // node_update blocks = N/4
#define TKNOT 4096         // table knots per unit range (len = k * 5/4096)
#define TROWS 4097         // knots 0..4096 (4096 = len 5.0 exactly => R(ef=0))
#define TPAD  4100         // padded row stride
#define TBLK  2049         // ceil(2*4097/4) table-builder blocks (4 waves each)

typedef __attribute__((ext_vector_type(8))) short short8;
typedef __attribute__((ext_vector_type(4))) float f32x4;

__device__ __forceinline__ float wred(float v) {
    #pragma unroll
    for (int off = 32; off > 0; off >>= 1) v += __shfl_down(v, off, 64);
    return v;
}

__device__ __forceinline__ float silu(float h) {
    return h / (1.f + __expf(-h));
}

// bijective XCD-aware block swizzle (m204 form); contiguous chunk per XCD
__device__ __forceinline__ int xcd_swizzle(int bid, int nb) {
    int q = nb >> 3, r = nb & 7;
    int x = bid & 7, i = bid >> 3;
    return (x < r ? x * (q + 1) : r * (q + 1) + (x - r) * q) + i;
}

// Receiver histogram only (tiny; runs before scan).
__global__ __launch_bounds__(256) void hist_k(
    const int* __restrict__ eidx, int* __restrict__ cnt, int E_)
{
    int e = blockIdx.x * 256 + threadIdx.x;
    atomicAdd(&cnt[eidx[E_ + e]], 1);
}

// Single-block shuffle scan (pure prefix-sum of receiver counts).
__global__ __launch_bounds__(1024) void scan_k(
    const int* __restrict__ cnt, int* __restrict__ cur, int N_)
{
    int t = threadIdx.x;
    __shared__ int wtot[16];
    int lane = t & 63, wid = t >> 6;
    int base = t * 20;
    int c[20]; int s = 0;
    bool full = (base + 20 <= N_);
    if (full) {
        #pragma unroll
        for (int i = 0; i < 5; ++i) {
            int4 v4 = *(const int4*)&cnt[base + i * 4];
            c[i*4+0] = v4.x; c[i*4+1] = v4.y; c[i*4+2] = v4.z; c[i*4+3] = v4.w;
        }
        #pragma unroll
        for (int i = 0; i < 20; ++i) s += c[i];
    } else {
        #pragma unroll
        for (int i = 0; i < 20; ++i) { int idx = base + i; c[i] = (idx < N_) ? cnt[idx] : 0; s += c[i]; }
    }
    int v = s;
    #pragma unroll
    for (int off = 1; off < 64; off <<= 1) {
        int u = __shfl_up(v, off, 64);
        if (lane >= off) v += u;
    }
    if (lane == 63) wtot[wid] = v;
    __syncthreads();
    if (wid == 0 && lane < 16) {
        int wv = wtot[lane];
        #pragma unroll
        for (int off = 1; off < 16; off <<= 1) {
            int u = __shfl_up(wv, off, 64);
            if (lane >= off) wv += u;
        }
        wtot[lane] = wv;
    }
    __syncthreads();
    int ex = (wid > 0 ? wtot[wid - 1] : 0) + (v - s);
    if (full) {
        int o[20];
        #pragma unroll
        for (int i = 0; i < 20; ++i) { o[i] = ex; ex += c[i]; }
        #pragma unroll
        for (int i = 0; i < 5; ++i)
            *(int4*)&cur[base + i * 4] = make_int4(o[i*4+0], o[i*4+1], o[i*4+2], o[i*4+3]);
    } else {
        #pragma unroll
        for (int i = 0; i < 20; ++i) {
            int idx = base + i;
            if (idx < N_) { cur[idx] = ex; ex += c[i]; }
        }
    }
}

// Fused: blocks [0,EGB) = geom scatter ({snd|rcv, len} 8B record at sorted slot);
// [EGB, EGB+TBLK) = radial-MLP table build (one wave per (layer,knot));
// [EGB+TBLK, ...) = node init (scal/spec/q/E0). Setup hides under the scatter.
__global__ __launch_bounds__(256) void setup_geom_k(
    const float* __restrict__ pos, const int* __restrict__ eidx,
    const float* __restrict__ flux_w, int* __restrict__ cur,
    uint2* __restrict__ recs, float* __restrict__ polpart,
    const float* __restrict__ attrs, const float* __restrict__ ae,
    const float* __restrict__ fc, const float* __restrict__ embed_w,
    int* __restrict__ spec, float* __restrict__ q, float* __restrict__ out,
    float* __restrict__ scal,
    const float* __restrict__ w1, const float* __restrict__ b1,
    const float* __restrict__ w2, float* __restrict__ tab,
    int N_, int E_, int ng)
{
    int bid = blockIdx.x, t = threadIdx.x;
    const float PI = 3.14159265358979323846f;
    if (bid < EGB) {
        // ---- geom scatter path (1 edge/thread) ----
        __shared__ float lpol[GG * 3];
        for (int i = t; i < GG * 3; i += 256) lpol[i] = 0.f;
        __syncthreads();
        int e = bid * 256 + t;
        if (e < E_) {
            float fw[NBES];
            #pragma unroll
            for (int i = 0; i < NBES; ++i) fw[i] = flux_w[i] + flux_w[NBES + i];
            unsigned int magic = (unsigned int)(0xFFFFFFFFull / (unsigned int)ng) + 1u;
            int s = eidx[e], r = eidx[E_ + e];
            float dx = pos[(size_t)r*3+0] - pos[(size_t)s*3+0];
            float dy = pos[(size_t)r*3+1] - pos[(size_t)s*3+1];
            float dz = pos[(size_t)r*3+2] - pos[(size_t)s*3+2];
            float len = sqrtf(dx*dx + dy*dy + dz*dz + 1e-12f);
            float x = len * 0.2f;
            float u = 0.f;
            if (x < 1.f) {
                float x2 = x * x;
                float x5 = x2 * x2 * x;
                u = 1.f - 21.f * x5 + 35.f * x5 * x - 15.f * x5 * x2;
            }
            float pref = 0.6324555320336759f / len * u;
            float theta = PI * x;
            float s1, c1;
            __sincosf(theta, &s1, &c1);
            float c2 = 2.f * c1;
            float sp_ = 0.f, sn = s1;
            float flux = 0.f;
            #pragma unroll
            for (int i = 0; i < NBES; ++i) {
                flux += pref * sn * fw[i];
                float n1 = c2 * sn - sp_; sp_ = sn; sn = n1;
            }
            int p = atomicAdd(&cur[r], 1);
            recs[p] = make_uint2((unsigned int)s | ((unsigned int)r << 16),
                                 __float_as_uint(len));
            int g = (int)__umulhi((unsigned int)r, magic);
            atomicAdd(&lpol[g*3+0], flux * dx);
            atomicAdd(&lpol[g*3+1], flux * dy);
            atomicAdd(&lpol[g*3+2], flux * dz);
        }
        __syncthreads();
        for (int i = t; i < GG * 3; i += 256) polpart[bid * (GG * 3) + i] = lpol[i];
    } else if (bid < EGB + TBLK) {
        // ---- radial-MLP table build: wave (l,kk) -> tab[l][kk][0..63] ----
        if (bid == EGB && t < GG) out[t] = 0.f;   // total-energy accumulators
        int widg = (bid - EGB) * 4 + (t >> 6);
        if (widg < 2 * TROWS) {
            int l = widg / TROWS;
            int kk = widg - l * TROWS;
            int f = t & 63;
            float len = fmaxf((float)kk * (5.f / (float)TKNOT), 1e-6f);
            float x = len * 0.2f;
            float u = 0.f;
            if (x < 1.f) {
                float x2 = x * x;
                float x5 = x2 * x2 * x;
                u = 1.f - 21.f * x5 + 35.f * x5 * x - 15.f * x5 * x2;
            }
            float pref = 0.6324555320336759f / len * u;
            float theta = PI * x;
            float s1, c1;
            __sincosf(theta, &s1, &c1);
            float c2 = 2.f * c1;
            float sp_ = 0.f, sn = s1;
            float ef[NBES];
            #pragma unroll
            for (int i = 0; i < NBES; ++i) {
                ef[i] = pref * sn;
                float n1 = c2 * sn - sp_; sp_ = sn; sn = n1;
            }
            float h = b1[l * FD + f];
            #pragma unroll
            for (int j = 0; j < NBES; ++j)
                h = fmaf(ef[j], w1[l * 512 + j * 64 + f], h);
            h = silu(h);
            float o = 0.f;
            #pragma unroll
            for (int m = 0; m < 64; ++m)
                o = fmaf(__shfl(h, m, 64), w2[(size_t)l * 4096 + m * 64 + f], o);
            tab[((size_t)l * TPAD + kk) * 64 + f] = o;
        }
    } else {
        // ---- node init: scal embed, spec, q=fc, E0 ----
        int idx = (bid - (EGB + TBLK)) * 256 + t;
        int lane = t & 63;
        int n = idx >> 6;
        bool pred = (lane < NEL) && (attrs[(size_t)n * NEL + lane] > 0.5f);
        unsigned long long m = __ballot(pred);
        int sp = (int)__builtin_ctzll(m);
        scal[idx] = embed_w[sp * FD + lane];
        if (lane == 0) { spec[n] = sp; q[n] = fc[sp]; out[GG + n] = ae[sp]; }
    }
}

// Edge pass v2: radial MLP via table lerp (R_l(len) is a smooth 1-D function;
// f32 lerp error ~5e-5 << the old path's bf16 rounding). Per edge: 2 coalesced
// table-row loads + 1 scal gather + fma. No MFMA, no LDS, no bessel storage.
// 64 edges/wave, segmented reduce: interior runs plain-store, boundary atomics.
__global__ __launch_bounds__(256, 4) void edge_mlp_k(
    const uint2* __restrict__ recs, const float* __restrict__ tab,
    const float* __restrict__ scal, float* __restrict__ agg0, int layer, int E_)
{
    int t = threadIdx.x, w = t >> 6, lane = t & 63;
    int xb = xcd_swizzle(blockIdx.x, gridDim.x);
    int wbase = (xb * 4 + w) * 64;
    const float* tb = tab + (size_t)layer * TPAD * 64;

    uint2 rec = recs[wbase + lane];          // one coalesced 8B load = 64 edges
    // per-lane knot precompute for this lane's own edge
    float ln = __uint_as_float(rec.y);
    float tt = ln * ((float)TKNOT / 5.f);
    int k0l = min((int)tt, TKNOT - 1);
    float frl = fminf(tt - (float)k0l, 1.f);
    int offl = k0l * 64;

    int firstR = (int)(__builtin_amdgcn_readlane(rec.x, 0) >> 16);
    int curR = firstR;
    float run = 0.f;

    #pragma unroll 1
    for (int grp = 0; grp < 4; ++grp) {
        unsigned int idv[16];
        int off[16];
        float fr[16];
        #pragma unroll
        for (int k = 0; k < 16; ++k) {
            int pp = grp * 16 + k;
            idv[k] = __builtin_amdgcn_readlane(rec.x, pp);
            off[k] = __builtin_amdgcn_readlane(offl, pp);
            fr[k]  = __uint_as_float((unsigned int)__builtin_amdgcn_readlane(
                         __float_as_uint(frl), pp));
        }
        float ra[16], rb[16], sw[16];
        #pragma unroll
        for (int k = 0; k < 16; ++k) {
            ra[k] = tb[off[k] + lane];
            rb[k] = tb[off[k] + 64 + lane];
            sw[k] = scal[(size_t)(idv[k] & 0xffffu) * FD + lane];
        }
        #pragma unroll
        for (int k = 0; k < 16; ++k) {
            int r = (int)(idv[k] >> 16);
            float R = fmaf(fr[k], rb[k] - ra[k], ra[k]);
            float v = R * sw[k];
            if (r != curR) {
                float* dst = &agg0[(size_t)curR * FD + lane];
                if (curR != firstR) *dst = run;       // interior run: exclusive owner
                else atomicAdd(dst, run);             // wave-boundary run
                run = v; curR = r;
            } else {
                run += v;
            }
        }
    }
    atomicAdd(&agg0[(size_t)curR * FD + lane], run);       // trailing boundary run
}

// Node update + block-level energy partial (nEpart[layer][block]).
// Last-layer MLP wave-parallelized (R11): quarter-partials + 2 shfl folds.
__global__ __launch_bounds__(256) void node_update_k(
    float* __restrict__ scal, float* __restrict__ agg0,
    const int* __restrict__ spec, const float* __restrict__ prod_w,
    const float* __restrict__ readout_w, const float* __restrict__ ro2_w1,
    const float* __restrict__ ro2_b1, const float* __restrict__ ro2_w2,
    const float* __restrict__ charge_w, float* __restrict__ q,
    float* __restrict__ out_nodeE, float* __restrict__ nEpart,
    int layer, int last, int N_)
{
    __shared__ float vsh[4][FD];
    __shared__ float red[4];
    int wid = threadIdx.x >> 6, lane = threadIdx.x & 63;
    int n = blockIdx.x * 4 + wid;
    int sp = spec[n];
    size_t idx = (size_t)n * FD + lane;
    float a = agg0[idx] * 0.0625f;
    if (!last) agg0[idx] = 0.f;            // last layer: agg0 never read again
    float v = a + a * a + scal[idx] * prod_w[(layer * NEL + sp) * FD + lane];
    scal[idx] = v;

    float ne;
    if (!last) {
        ne = wred(v * readout_w[layer * FD + lane]);
    } else {
        vsh[wid][lane] = v;                    // wave-private, in-order DS
        int l16 = lane & 15, qq = lane >> 4;
        float hp = 0.f;
        #pragma unroll
        for (int ff = 0; ff < 16; ++ff) {
            int fidx = qq * 16 + ff;
            hp += vsh[wid][fidx] * ro2_w1[fidx * HML + l16];
        }
        hp += __shfl_down(hp, 32, 64);
        hp += __shfl_down(hp, 16, 64);         // lanes 0..15 hold full sum
        float h = 0.f;
        if (lane < HML) h = silu(ro2_b1[lane] + hp) * ro2_w2[lane];
        ne = wred(h);
    }
    float qs = wred(v * charge_w[layer * FD + lane]);
    if (lane == 0) {
        out_nodeE[n] += ne;
        q[n] += qs;
        red[wid] = ne;
    }
    __syncthreads();
    if (threadIdx.x == 0) nEpart[layer * NUB + blockIdx.x] = red[0] + red[1] + red[2] + red[3];
}

// Coulomb via triangular 64x64 chunk pairs (136/graph) + 1 reduce block/graph.
__global__ __launch_bounds__(256) void coulomb_final_k(
    const float* __restrict__ q, const float* __restrict__ pos,
    const int* __restrict__ spec, const float* __restrict__ ae,
    const float* __restrict__ fc, const float* __restrict__ nEpart,
    const float* __restrict__ polpart, float* __restrict__ out,
    int N_, int ng)
{
    __shared__ float sh[260];
    int vb = blockIdx.x;
    int g = vb / 137, rem = vb % 137;
    int t = threadIdx.x, lane = t & 63, w = t >> 6;

    if (rem < 136) {
        int a = 0, r2 = rem;
        while (r2 >= 16 - a) { r2 -= 16 - a; ++a; }
        int b = a + r2;
        const float* qg = q + (size_t)g * ng;
        const float* pg = pos + (size_t)g * ng * 3;
        float* qs_ = sh; float* jx = sh + 64; float* jy = sh + 128; float* jz = sh + 192;
        if (t < 64) {
            int j = b * 64 + t;
            bool ok = j < ng;
            qs_[t] = ok ? qg[j] : 0.f;
            jx[t] = ok ? pg[(size_t)j*3+0] : 0.f;
            jy[t] = ok ? pg[(size_t)j*3+1] : 0.f;
            jz[t] = ok ? pg[(size_t)j*3+2] : 0.f;
        }
        __syncthreads();
        int i = a * 64 + lane;
        float accu = 0.f;
        if (i < ng) {
            float qi = qg[i];
            float xi = pg[(size_t)i*3+0], yi = pg[(size_t)i*3+1], zi = pg[(size_t)i*3+2];
            #pragma unroll 4
            for (int k = 0; k < 16; ++k) {
                int jj = w * 16 + k;                  // wave-uniform -> LDS broadcast
                int j = b * 64 + jj;
                float dx = xi - jx[jj], dy = yi - jy[jj], dz = zi - jz[jj];
                float d2 = dx*dx + dy*dy + dz*dz + 1e-12f;
                float rinv = __frsqrt_rn(d2);
                float r = d2 * rinv;
                float x = 0.5f * r;
                float tt = __frcp_rn(1.f + 0.3275911f * x);
                float poly = ((((1.061405429f*tt - 1.453152027f)*tt + 1.421413741f)*tt
                               - 0.284496736f)*tt + 0.254829592f)*tt;
                float erfv = 1.f - poly * __expf(-x * x);
                float kern = (j == i) ? 0.f : erfv * rinv;
                accu += qi * qs_[jj] * kern;
            }
        }
        accu = wred(accu);
        if (lane == 0) sh[256 + w] = accu;
        __syncthreads();
        if (t == 0) {
            float s = sh[256] + sh[257] + sh[258] + sh[259];
            atomicAdd(&out[g], (a == b) ? 0.5f * s : s);
        }
    } else {
        float se0 = 0.f, sq = 0.f, p0 = 0.f, p1 = 0.f, p2 = 0.f, s0 = 0.f, s1 = 0.f;
        for (int n = g * ng + t; n < (g + 1) * ng; n += 256) {
            int sp = spec[n];
            float fq = fc[sp];
            se0 += ae[sp];
            sq += q[n];
            p0 += fq * pos[(size_t)n*3+0];
            p1 += fq * pos[(size_t)n*3+1];
            p2 += fq * pos[(size_t)n*3+2];
        }
        if (t < 250) {
            int b = g * 250 + t;
            s0 = nEpart[b];
            s1 = nEpart[NUB + b];
        }
        for (int b = t; b < EGB; b += 256) {
            p0 += polpart[b * (GG * 3) + g * 3 + 0];
            p1 += polpart[b * (GG * 3) + g * 3 + 1];
            p2 += polpart[b * (GG * 3) + g * 3 + 2];
        }
        float vals[7] = {se0, s0, s1, sq, p0, p1, p2};
        float* red = sh;
        #pragma unroll
        for (int k = 0; k < 7; ++k) {
            float r = wred(vals[k]);
            if (lane == 0) red[w * 8 + k] = r;
        }
        __syncthreads();
        if (t < 7) sh[64 + t] = red[t] + red[8 + t] + red[16 + t] + red[24 + t];
        __syncthreads();
        if (t == 0) {
            float a0 = sh[64], a1 = sh[65], a2 = sh[66];
            atomicAdd(&out[g], a0 + a1 + a2);
            float* contrib = out + GG + N_;
            contrib[g*3+0] = a0; contrib[g*3+1] = a1; contrib[g*3+2] = a2;
            float* pol = contrib + GG * 3;
            pol[g*3+0] = sh[68]; pol[g*3+1] = sh[69]; pol[g*3+2] = sh[70];
            float* qt = pol + GG * 3;
            qt[g] = sh[67];
        }
    }
}

extern "C" void kernel_launch(void* const* d_in, const int* in_sizes, int n_in,
                              void* d_out, int out_size, void* d_ws, size_t ws_size,
                              hipStream_t stream)
{
    const float* node_attrs      = (const float*)d_in[0];
    const float* positions       = (const float*)d_in[1];
    const int*   edge_index      = (const int*)d_in[2];
    const float* atomic_energies = (const float*)d_in[5];
    const float* embed_w         = (const float*)d_in[6];
    const float* radial_w1       = (const float*)d_in[7];
    const float* radial_b1       = (const float*)d_in[8];
    const float* radial_w2       = (const float*)d_in[9];
    const float* prod_w          = (const float*)d_in[10];
    const float* readout_w       = (const float*)d_in[11];
    const float* ro2_w1          = (const float*)d_in[12];
    const float* ro2_b1          = (const float*)d_in[13];
    const float* ro2_w2          = (const float*)d_in[14];
    const float* charge_w        = (const float*)d_in[15];
    const float* flux_w          = (const float*)d_in[16];
    const float* formal_charges  = (const float*)d_in[17];

    int N = in_sizes[0] / NEL;     // 20000
    int E = in_sizes[2] / 2;       // 320000
    int ng = N / GG;               // 1000

    float* ws      = (float*)d_ws;
    float* scal    = ws;                                   // [N,64]
    float* agg0    = scal + (size_t)N * FD;                // [N,64]  (memset)
    int*   cnt     = (int*)(agg0 + (size_t)N * FD);        // [N]     (memset, adjacent)
    int*   cur     = cnt + N;                              // [N]
    uint2* recs    = (uint2*)(cur + N);                    // [E] {snd|rcv<<16, len} sorted
    float* q       = (float*)(recs + E);                   // [N]
    int*   spec    = (int*)(q + N);                        // [N]
    float* nEpart  = (float*)(spec + N);                   // [2*NUB]
    float* polpart = nEpart + 2 * NUB;                     // [EGB*60]
    float* tab     = polpart + EGB * (GG * 3);             // [2,TPAD,64] radial table

    float* out = (float*)d_out;
    float* out_nodeE = out + GG;

    // one memset covers agg0 (zero-init for scatter) + cnt (histogram)
    hipMemsetAsync(agg0, 0, ((size_t)N * FD + N) * sizeof(float), stream);

    hist_k<<<E / 256, 256, 0, stream>>>(edge_index, cnt, E);
    scan_k<<<1, 1024, 0, stream>>>(cnt, cur, N);
    setup_geom_k<<<EGB + TBLK + (N * FD) / 256, 256, 0, stream>>>(
        positions, edge_index, flux_w, cur, recs, polpart,
        node_attrs, atomic_energies, formal_charges, embed_w,
        spec, q, out, scal, radial_w1, radial_b1, radial_w2, tab, N, E, ng);

    for (int l = 0; l < 2; ++l) {
        edge_mlp_k<<<E / 256, 256, 0, stream>>>(
            recs, tab, scal, agg0, l, E);
        node_update_k<<<N / 4, 256, 0, stream>>>(
            scal, agg0, spec, prod_w, readout_w, ro2_w1, ro2_b1, ro2_w2,
            charge_w, q, out_nodeE, nEpart, l, (l == 1) ? 1 : 0, N);
    }

    coulomb_final_k<<<GG * 137, 256, 0, stream>>>(
        q, positions, spec, atomic_energies, formal_charges,
        nEpart, polpart, out, N, ng);
}